// Round 1
// baseline (386.927 us; speedup 1.0000x reference)
//
#include <hip/hip_runtime.h>
#include <hip/hip_bf16.h>
#include <cstdint>
#include <cstddef>

#define DIM_ 2048
#define SLEN 2048
#define NQH 32
#define NKVH 8
#define HDIM 64
#define KVDIM 512

typedef __attribute__((ext_vector_type(8))) short short8;
typedef __attribute__((ext_vector_type(4))) float f32x4;

__device__ __forceinline__ unsigned short f2bf(float f) {
  unsigned u = __builtin_bit_cast(unsigned, f);
  u += 0x7FFFu + ((u >> 16) & 1u);
  return (unsigned short)(u >> 16);
}

__device__ __forceinline__ void gload_lds16(const void* g, void* l) {
  __builtin_amdgcn_global_load_lds(
      (const __attribute__((address_space(1))) void*)g,
      (__attribute__((address_space(3))) void*)l, 16, 0, 0);
}

// ---------------- fp32 -> bf16 convert (8 elems/thread, RNE) ----------------
__global__ void cvt_bf16_kernel(const float* __restrict__ in,
                                unsigned short* __restrict__ out, int n) {
  int i = (blockIdx.x * blockDim.x + threadIdx.x) * 8;
  if (i >= n) return;
  float4 a = *(const float4*)(in + i);
  float4 b = *(const float4*)(in + i + 4);
  ushort4 o0, o1;
  o0.x = f2bf(a.x); o0.y = f2bf(a.y); o0.z = f2bf(a.z); o0.w = f2bf(a.w);
  o1.x = f2bf(b.x); o1.y = f2bf(b.y); o1.z = f2bf(b.z); o1.w = f2bf(b.w);
  *(ushort4*)(out + i) = o0;
  *(ushort4*)(out + i + 4) = o1;
}

// ---------------- RoPE tables: cos/sin (SLEN x 32) fp32 ----------------
__global__ void rope_table_kernel(float* __restrict__ cosT, float* __restrict__ sinT) {
  int idx = blockIdx.x * blockDim.x + threadIdx.x;  // SLEN*32
  int s = idx >> 5, i = idx & 31;
  // inv_freq = 10000^(-i/32) = exp(-(i/32)*ln(10000))
  float inv = expf(-(float)i * (9.210340371976184f / 32.0f));
  float fr = (float)s * inv;
  cosT[idx] = cosf(fr);
  sinT[idx] = sinf(fr);
}

// ---------------- RoPE apply: fp32 in, bf16 out ----------------
__global__ void rope_apply_kernel(const float* __restrict__ Xf,
                                  unsigned short* __restrict__ Xr,
                                  const float* __restrict__ cosT,
                                  const float* __restrict__ sinT, int nheads) {
  int idx = blockIdx.x * blockDim.x + threadIdx.x;
  int i = idx & 31;
  int t = idx >> 5;
  int hh = t & (nheads - 1);   // nheads is 32 or 8 (pow2)
  int s = t / nheads;
  size_t base = (size_t)s * ((size_t)nheads * 64) + (size_t)hh * 64;
  float c = cosT[(s << 5) + i], sn = sinT[(s << 5) + i];
  float x1 = Xf[base + i], x2 = Xf[base + i + 32];
  Xr[base + i]      = f2bf(x1 * c - x2 * sn);
  Xr[base + i + 32] = f2bf(x2 * c + x1 * sn);
}

// ---------------- bt-GEMM: C[m,n] = sum_k A[m,k]*B[n,k]  (m97 structure) ----
// A: (2048 x 2048) bf16 row-major. B: (NCOLS x 2048) bf16 row-major.
// OMODE: 0 = fp32 C[m*NCOLS+n]; 1 = bf16 C[m*NCOLS+n]; 2 = bf16 C[n*SLEN+m] (transposed)
template <int NCOLS, int OMODE>
__global__ __launch_bounds__(256, 2)
void gemm_bt(const unsigned short* __restrict__ A,
             const unsigned short* __restrict__ B, void* __restrict__ Cp) {
  constexpr int K = DIM_;
  __shared__ unsigned short sA[128 * 32];
  __shared__ unsigned short sB[128 * 32];
  const int tid = threadIdx.x;
  const int wv = tid >> 6, ln = tid & 63;
  const int row0 = blockIdx.x * 128;
  const int col0 = blockIdx.y * 128;
  const int wr = (wv >> 1) * 64, wc = (wv & 1) * 64;
  const int lrow = ln & 15, lk = (ln >> 4) * 8;
  f32x4 acc[4][4] = {};

  for (int kt = 0; kt < K; kt += 32) {
#pragma unroll
    for (int r = 0; r < 2; ++r) {
      int e = (r * 256 + tid) * 8;
      int rr = e >> 5, cc = e & 31;
      gload_lds16(A + (size_t)(row0 + rr) * K + kt + cc,
                  sA + (size_t)(r * 256 + wv * 64) * 8);
      gload_lds16(B + (size_t)(col0 + rr) * K + kt + cc,
                  sB + (size_t)(r * 256 + wv * 64) * 8);
    }
    __syncthreads();
    short8 af[4], bfr[4];
#pragma unroll
    for (int m = 0; m < 4; ++m)
      af[m] = *(const short8*)(sA + (wr + m * 16 + lrow) * 32 + lk);
#pragma unroll
    for (int n = 0; n < 4; ++n)
      bfr[n] = *(const short8*)(sB + (wc + n * 16 + lrow) * 32 + lk);
#pragma unroll
    for (int m = 0; m < 4; ++m)
#pragma unroll
      for (int n = 0; n < 4; ++n)
        acc[m][n] = __builtin_amdgcn_mfma_f32_16x16x32_bf16(af[m], bfr[n],
                                                            acc[m][n], 0, 0, 0);
    __syncthreads();
  }
  const int orow = (ln >> 4) * 4;
#pragma unroll
  for (int m = 0; m < 4; ++m) {
#pragma unroll
    for (int n = 0; n < 4; ++n) {
#pragma unroll
      for (int j = 0; j < 4; ++j) {
        int row = row0 + wr + m * 16 + orow + j;
        int col = col0 + wc + n * 16 + lrow;
        float v = acc[m][n][j];
        if (OMODE == 0)
          ((float*)Cp)[(size_t)row * NCOLS + col] = v;
        else if (OMODE == 1)
          ((unsigned short*)Cp)[(size_t)row * NCOLS + col] = f2bf(v);
        else
          ((unsigned short*)Cp)[(size_t)col * SLEN + row] = f2bf(v);
      }
    }
  }
}

// ---------------- Flash attention (causal, GQA) ----------------
// Q: (SLEN x 2048) bf16 roped. Kc: (SLEN x 512) bf16 roped. Vt: (512 x SLEN) bf16.
// AO: (SLEN x 2048) bf16.  grid = (32 q-tiles, 32 heads), 256 threads.
__global__ __launch_bounds__(256, 2)
void attn_kernel(const unsigned short* __restrict__ Q,
                 const unsigned short* __restrict__ Kc,
                 const unsigned short* __restrict__ Vt,
                 unsigned short* __restrict__ AO) {
  const int qt = blockIdx.x;
  const int h = blockIdx.y;
  const int kvh = h >> 2;
  const int q0 = qt * 64;
  const int tid = threadIdx.x;
  const int wv = tid >> 6, ln = tid & 63;
  const int qw = q0 + wv * 16;  // this wave's 16 q rows
  const int lrow = ln & 15, lg = ln >> 4;

  __shared__ unsigned short sK[64][72];      // [kpos][d]  (+8 pad)
  __shared__ unsigned short sV[64][72];      // [d][kpos]  (+8 pad)
  __shared__ unsigned short sP[4][16][72];   // per-wave P rows

  short8 qf[2];
  {
    const unsigned short* qp =
        Q + (size_t)(qw + lrow) * DIM_ + h * HDIM + lg * 8;
    qf[0] = *(const short8*)qp;
    qf[1] = *(const short8*)(qp + 32);
  }
  f32x4 o[4] = {};
  float mrun[4], lrun[4];
#pragma unroll
  for (int j = 0; j < 4; ++j) { mrun[j] = -1e30f; lrun[j] = 0.f; }

  for (int kt = 0; kt <= qt; ++kt) {
    const int k0 = kt * 64;
    __syncthreads();
#pragma unroll
    for (int r = 0; r < 2; ++r) {
      int e = (r * 256 + tid) * 8;
      int rr = e >> 6, cc = e & 63;
      short8 kk = *(const short8*)(Kc + (size_t)(k0 + rr) * KVDIM + kvh * HDIM + cc);
      short8 vvv = *(const short8*)(Vt + (size_t)(kvh * HDIM + rr) * SLEN + k0 + cc);
      *(short8*)&sK[rr][cc] = kk;
      *(short8*)&sV[rr][cc] = vvv;
    }
    __syncthreads();

    // scores: S = Q(16x64) @ K_tile^T -> 16x64
    f32x4 sc[4] = {};
#pragma unroll
    for (int f = 0; f < 4; ++f) {
#pragma unroll
      for (int kb = 0; kb < 2; ++kb) {
        short8 kfrag = *(const short8*)&sK[f * 16 + lrow][kb * 32 + lg * 8];
        sc[f] = __builtin_amdgcn_mfma_f32_16x16x32_bf16(qf[kb], kfrag, sc[f], 0, 0, 0);
      }
    }
    // scale + causal mask + row max
    float mx[4];
#pragma unroll
    for (int j = 0; j < 4; ++j) mx[j] = -1e30f;
    const bool diag = (kt == qt);
#pragma unroll
    for (int f = 0; f < 4; ++f) {
#pragma unroll
      for (int j = 0; j < 4; ++j) {
        float v = sc[f][j] * 0.125f;
        if (diag && (k0 + f * 16 + lrow) > (qw + lg * 4 + j)) v = -1e30f;
        sc[f][j] = v;
        mx[j] = fmaxf(mx[j], v);
      }
    }
#pragma unroll
    for (int j = 0; j < 4; ++j) {
      mx[j] = fmaxf(mx[j], __shfl_xor(mx[j], 1));
      mx[j] = fmaxf(mx[j], __shfl_xor(mx[j], 2));
      mx[j] = fmaxf(mx[j], __shfl_xor(mx[j], 4));
      mx[j] = fmaxf(mx[j], __shfl_xor(mx[j], 8));
    }
    float alpha[4], rsum[4];
#pragma unroll
    for (int j = 0; j < 4; ++j) {
      float mnew = fmaxf(mrun[j], mx[j]);
      alpha[j] = __expf(mrun[j] - mnew);
      mrun[j] = mnew;
      rsum[j] = 0.f;
    }
#pragma unroll
    for (int f = 0; f < 4; ++f) {
#pragma unroll
      for (int j = 0; j < 4; ++j) {
        float p = __expf(sc[f][j] - mrun[j]);
        rsum[j] += p;
        sP[wv][lg * 4 + j][f * 16 + lrow] = f2bf(p);
      }
    }
#pragma unroll
    for (int j = 0; j < 4; ++j) {
      rsum[j] += __shfl_xor(rsum[j], 1);
      rsum[j] += __shfl_xor(rsum[j], 2);
      rsum[j] += __shfl_xor(rsum[j], 4);
      rsum[j] += __shfl_xor(rsum[j], 8);
      lrun[j] = lrun[j] * alpha[j] + rsum[j];
    }
#pragma unroll
    for (int n = 0; n < 4; ++n)
#pragma unroll
      for (int j = 0; j < 4; ++j) o[n][j] *= alpha[j];

    // PV: O += P(16x64) @ V(64x64)
#pragma unroll
    for (int kb = 0; kb < 2; ++kb) {
      short8 pa = *(const short8*)&sP[wv][lrow][kb * 32 + lg * 8];
#pragma unroll
      for (int n = 0; n < 4; ++n) {
        short8 vb = *(const short8*)&sV[n * 16 + lrow][kb * 32 + lg * 8];
        o[n] = __builtin_amdgcn_mfma_f32_16x16x32_bf16(pa, vb, o[n], 0, 0, 0);
      }
    }
  }
  // epilogue: AO[row][h*64+d] = o / l
#pragma unroll
  for (int n = 0; n < 4; ++n) {
#pragma unroll
    for (int j = 0; j < 4; ++j) {
      int row = qw + lg * 4 + j;
      int d = n * 16 + lrow;
      AO[(size_t)row * DIM_ + h * HDIM + d] = f2bf(o[n][j] / lrun[j]);
    }
  }
}

extern "C" void kernel_launch(void* const* d_in, const int* in_sizes, int n_in,
                              void* d_out, int out_size, void* d_ws, size_t ws_size,
                              hipStream_t stream) {
  const float* x  = (const float*)d_in[0];
  const float* wq = (const float*)d_in[1];
  const float* wk = (const float*)d_in[2];
  const float* wv = (const float*)d_in[3];
  const float* wo = (const float*)d_in[4];
  float* out = (float*)d_out;
  char* ws = (char*)d_ws;
  const size_t MB = 1u << 20;
  unsigned short* bx  = (unsigned short*)(ws + 0 * MB);    // 8 MB
  unsigned short* bwq = (unsigned short*)(ws + 8 * MB);    // 8 MB
  unsigned short* bwk = (unsigned short*)(ws + 16 * MB);   // 2 MB
  unsigned short* bwv = (unsigned short*)(ws + 18 * MB);   // 2 MB
  unsigned short* bwo = (unsigned short*)(ws + 20 * MB);   // 8 MB
  float*          Qf  = (float*)(ws + 28 * MB);            // 16 MB
  float*          Kf  = (float*)(ws + 44 * MB);            // 4 MB
  unsigned short* Qr  = (unsigned short*)(ws + 48 * MB);   // 8 MB
  unsigned short* Kr  = (unsigned short*)(ws + 56 * MB);   // 2 MB
  unsigned short* Vt  = (unsigned short*)(ws + 58 * MB);   // 2 MB
  unsigned short* AO  = (unsigned short*)(ws + 60 * MB);   // 8 MB
  float* cosT = (float*)(ws + 68 * MB);                    // 256 KB
  float* sinT = (float*)(ws + 68 * MB + 256 * 1024);       // 256 KB

  rope_table_kernel<<<SLEN * 32 / 256, 256, 0, stream>>>(cosT, sinT);
  cvt_bf16_kernel<<<(2048 * 2048 / 8) / 256, 256, 0, stream>>>(x, bx, 2048 * 2048);
  cvt_bf16_kernel<<<(2048 * 2048 / 8) / 256, 256, 0, stream>>>(wq, bwq, 2048 * 2048);
  cvt_bf16_kernel<<<(512 * 2048 / 8) / 256, 256, 0, stream>>>(wk, bwk, 512 * 2048);
  cvt_bf16_kernel<<<(512 * 2048 / 8) / 256, 256, 0, stream>>>(wv, bwv, 512 * 2048);
  cvt_bf16_kernel<<<(2048 * 2048 / 8) / 256, 256, 0, stream>>>(wo, bwo, 2048 * 2048);

  gemm_bt<2048, 0><<<dim3(16, 16), 256, 0, stream>>>(bx, bwq, Qf);
  gemm_bt<512, 0><<<dim3(16, 4), 256, 0, stream>>>(bx, bwk, Kf);
  gemm_bt<512, 2><<<dim3(16, 4), 256, 0, stream>>>(bx, bwv, Vt);

  rope_apply_kernel<<<(SLEN * NQH * 32) / 256, 256, 0, stream>>>(Qf, Qr, cosT, sinT, NQH);
  rope_apply_kernel<<<(SLEN * NKVH * 32) / 256, 256, 0, stream>>>(Kf, Kr, cosT, sinT, NKVH);

  attn_kernel<<<dim3(32, 32), 256, 0, stream>>>(Qr, Kr, Vt, AO);

  gemm_bt<2048, 0><<<dim3(16, 16), 256, 0, stream>>>(AO, bwo, out);
}

// Round 3
// 253.326 us; speedup vs baseline: 1.5274x; 1.5274x over previous
//
#include <hip/hip_runtime.h>
#include <hip/hip_bf16.h>
#include <cstdint>
#include <cstddef>

#define DIM_ 2048
#define SLEN 2048
#define NQH 32
#define NKVH 8
#define HDIM 64
#define KVDIM 512

typedef __attribute__((ext_vector_type(8))) short short8;
typedef __attribute__((ext_vector_type(4))) float f32x4;
typedef __attribute__((ext_vector_type(16))) float f32x16;
typedef __attribute__((ext_vector_type(4))) unsigned int u32x4;

// 0.125 (1/sqrt(64)) * log2(e): scores land in log2 domain -> exp2 softmax
#define QSCALE 0.1803368801111243f

__device__ __forceinline__ unsigned short f2bf(float f) {
  unsigned u = __builtin_bit_cast(unsigned, f);
  u += 0x7FFFu + ((u >> 16) & 1u);
  return (unsigned short)(u >> 16);
}

__device__ __forceinline__ unsigned pack2bf(float a, float b) {
  return ((unsigned)f2bf(b) << 16) | (unsigned)f2bf(a);
}

__device__ __forceinline__ void gload_lds16(const void* g, void* l) {
  __builtin_amdgcn_global_load_lds(
      (const __attribute__((address_space(1))) void*)g,
      (__attribute__((address_space(3))) void*)l, 16, 0, 0);
}

// ---------------- fp32 -> bf16 convert (8 elems/thread, RNE) ----------------
__global__ void cvt_bf16_kernel(const float* __restrict__ in,
                                unsigned short* __restrict__ out, int n) {
  int i = (blockIdx.x * blockDim.x + threadIdx.x) * 8;
  if (i >= n) return;
  float4 a = *(const float4*)(in + i);
  float4 b = *(const float4*)(in + i + 4);
  ushort4 o0, o1;
  o0.x = f2bf(a.x); o0.y = f2bf(a.y); o0.z = f2bf(a.z); o0.w = f2bf(a.w);
  o1.x = f2bf(b.x); o1.y = f2bf(b.y); o1.z = f2bf(b.z); o1.w = f2bf(b.w);
  *(ushort4*)(out + i) = o0;
  *(ushort4*)(out + i + 4) = o1;
}

// ---------------- RoPE tables: cos/sin (SLEN x 32) fp32 ----------------
__global__ void rope_table_kernel(float* __restrict__ cosT, float* __restrict__ sinT) {
  int idx = blockIdx.x * blockDim.x + threadIdx.x;  // SLEN*32
  int s = idx >> 5, i = idx & 31;
  float inv = expf(-(float)i * (9.210340371976184f / 32.0f));
  float fr = (float)s * inv;
  cosT[idx] = cosf(fr);
  sinT[idx] = sinf(fr);
}

// ---------------- merged QKV GEMM with fused RoPE epilogue ----------------
// A: x (2048 x 2048) bf16. B: concat rows [wq;wk;wv] (3072 x 2048) bf16.
// by 0..15 -> Q (roped, *QSCALE, bf16 [s][h*64+d]); 16..19 -> K (roped, bf16
// [s][kvh*64+d]); 20..23 -> V transposed bf16 [kvh*64+d][s].
__global__ __launch_bounds__(256, 2)
void gemm_qkv(const unsigned short* __restrict__ A,
              const unsigned short* __restrict__ B,
              unsigned short* __restrict__ Qr,
              unsigned short* __restrict__ Kr,
              unsigned short* __restrict__ Vtp,
              const float* __restrict__ cosT,
              const float* __restrict__ sinT) {
  constexpr int K = DIM_;
  __shared__ unsigned short sA[128 * 32];
  __shared__ unsigned short sB[128 * 32];
  const int tid = threadIdx.x;
  const int wv = tid >> 6, ln = tid & 63;
  const int row0 = blockIdx.x * 128;
  const int col0 = blockIdx.y * 128;
  const int wr = (wv >> 1) * 64, wc = (wv & 1) * 64;
  const int lrow = ln & 15, lk = (ln >> 4) * 8;
  f32x4 acc[4][4] = {};

  for (int kt = 0; kt < K; kt += 32) {
#pragma unroll
    for (int r = 0; r < 2; ++r) {
      int e = (r * 256 + tid) * 8;
      int rr = e >> 5, cc = e & 31;
      gload_lds16(A + (size_t)(row0 + rr) * K + kt + cc,
                  sA + (size_t)(r * 256 + wv * 64) * 8);
      gload_lds16(B + (size_t)(col0 + rr) * K + kt + cc,
                  sB + (size_t)(r * 256 + wv * 64) * 8);
    }
    __syncthreads();
    short8 af[4], bfr[4];
#pragma unroll
    for (int m = 0; m < 4; ++m)
      af[m] = *(const short8*)(sA + (wr + m * 16 + lrow) * 32 + lk);
#pragma unroll
    for (int n = 0; n < 4; ++n)
      bfr[n] = *(const short8*)(sB + (wc + n * 16 + lrow) * 32 + lk);
#pragma unroll
    for (int m = 0; m < 4; ++m)
#pragma unroll
      for (int n = 0; n < 4; ++n)
        acc[m][n] = __builtin_amdgcn_mfma_f32_16x16x32_bf16(af[m], bfr[n],
                                                            acc[m][n], 0, 0, 0);
    __syncthreads();
  }
  const int orow = (ln >> 4) * 4;
  const int by = blockIdx.y;
  if (by < 16) {  // Q: RoPE + scale
#pragma unroll
    for (int m = 0; m < 4; ++m)
#pragma unroll
      for (int j = 0; j < 4; ++j) {
        const int s = row0 + wr + m * 16 + orow + j;
#pragma unroll
        for (int n = 0; n < 2; ++n) {
          const int d1 = n * 16 + lrow;  // 0..31
          const float cv = cosT[s * 32 + d1], sv = sinT[s * 32 + d1];
          const float x1 = acc[m][n][j], x2 = acc[m][n + 2][j];
          const size_t base = (size_t)s * DIM_ + col0 + wc + d1;
          Qr[base] = f2bf((x1 * cv - x2 * sv) * QSCALE);
          Qr[base + 32] = f2bf((x2 * cv + x1 * sv) * QSCALE);
        }
      }
  } else if (by < 20) {  // K: RoPE
    const int cb = col0 - 2048;
#pragma unroll
    for (int m = 0; m < 4; ++m)
#pragma unroll
      for (int j = 0; j < 4; ++j) {
        const int s = row0 + wr + m * 16 + orow + j;
#pragma unroll
        for (int n = 0; n < 2; ++n) {
          const int d1 = n * 16 + lrow;
          const float cv = cosT[s * 32 + d1], sv = sinT[s * 32 + d1];
          const float x1 = acc[m][n][j], x2 = acc[m][n + 2][j];
          const size_t base = (size_t)s * KVDIM + cb + wc + d1;
          Kr[base] = f2bf(x1 * cv - x2 * sv);
          Kr[base + 32] = f2bf(x2 * cv + x1 * sv);
        }
      }
  } else {  // V transposed
    const int cb = col0 - 2560;
#pragma unroll
    for (int m = 0; m < 4; ++m)
#pragma unroll
      for (int n = 0; n < 4; ++n)
#pragma unroll
        for (int j = 0; j < 4; ++j) {
          const int s = row0 + wr + m * 16 + orow + j;
          const int vc = cb + wc + n * 16 + lrow;
          Vtp[(size_t)vc * SLEN + s] = f2bf(acc[m][n][j]);
        }
  }
}

// ---------------- plain bt-GEMM (fp32 out) for O-projection ----------------
__global__ __launch_bounds__(256, 2)
void gemm_bt_f32(const unsigned short* __restrict__ A,
                 const unsigned short* __restrict__ B, float* __restrict__ C) {
  constexpr int K = DIM_;
  __shared__ unsigned short sA[128 * 32];
  __shared__ unsigned short sB[128 * 32];
  const int tid = threadIdx.x;
  const int wv = tid >> 6, ln = tid & 63;
  const int row0 = blockIdx.x * 128;
  const int col0 = blockIdx.y * 128;
  const int wr = (wv >> 1) * 64, wc = (wv & 1) * 64;
  const int lrow = ln & 15, lk = (ln >> 4) * 8;
  f32x4 acc[4][4] = {};
  for (int kt = 0; kt < K; kt += 32) {
#pragma unroll
    for (int r = 0; r < 2; ++r) {
      int e = (r * 256 + tid) * 8;
      int rr = e >> 5, cc = e & 31;
      gload_lds16(A + (size_t)(row0 + rr) * K + kt + cc,
                  sA + (size_t)(r * 256 + wv * 64) * 8);
      gload_lds16(B + (size_t)(col0 + rr) * K + kt + cc,
                  sB + (size_t)(r * 256 + wv * 64) * 8);
    }
    __syncthreads();
    short8 af[4], bfr[4];
#pragma unroll
    for (int m = 0; m < 4; ++m)
      af[m] = *(const short8*)(sA + (wr + m * 16 + lrow) * 32 + lk);
#pragma unroll
    for (int n = 0; n < 4; ++n)
      bfr[n] = *(const short8*)(sB + (wc + n * 16 + lrow) * 32 + lk);
#pragma unroll
    for (int m = 0; m < 4; ++m)
#pragma unroll
      for (int n = 0; n < 4; ++n)
        acc[m][n] = __builtin_amdgcn_mfma_f32_16x16x32_bf16(af[m], bfr[n],
                                                            acc[m][n], 0, 0, 0);
    __syncthreads();
  }
  const int orow = (ln >> 4) * 4;
#pragma unroll
  for (int m = 0; m < 4; ++m)
#pragma unroll
    for (int n = 0; n < 4; ++n)
#pragma unroll
      for (int j = 0; j < 4; ++j)
        C[(size_t)(row0 + wr + m * 16 + orow + j) * DIM_ + col0 + wc + n * 16 + lrow] =
            acc[m][n][j];
}

// ---------------- Flash attention: 4 warps x 32q, 32x32 swapped MFMA -------
// Q: [s][h*64+d] bf16, pre-scaled by QSCALE (log2 domain).
// Kc: [s][kvh*64+d] bf16 roped. Vt: [kvh*64+d][s] bf16. AO: [s][h*64+d] bf16.
// grid (8, 32); block b does chunk b (128 rows) then chunk 15-b => 34 tiles/block.
__global__ __launch_bounds__(256, 2)
void attn2_kernel(const unsigned short* __restrict__ Q,
                  const unsigned short* __restrict__ Kc,
                  const unsigned short* __restrict__ Vt,
                  unsigned short* __restrict__ AO) {
  __shared__ __align__(16) char smem[32768];  // [K dbuf 16K][V dbuf 16K]; sT overlays
  const int b = blockIdx.x, h = blockIdx.y;
  const int kvh = h >> 2;
  const int tid = threadIdx.x;
  const int w = tid >> 6, l = tid & 63;
  const int l31 = l & 31, hi = l >> 5;
  const int kvcol = kvh * HDIM;

  // staging: 2 x 16B per thread per 8KB tile; pre-swizzled global source so
  // linear global_load_lds + XOR'd ds_read are conflict-free (G4 / T2)
  int srow[2], scolb[2];
#pragma unroll
  for (int r = 0; r < 2; ++r) {
    int L = (r * 256 + tid) * 16;
    int row = L >> 7;
    srow[r] = row;
    scolb[r] = (L & 127) ^ ((row & 7) << 4);
  }

  for (int pass = 0; pass < 2; ++pass) {
    const int c = pass ? (15 - b) : b;
    const int nt = (c + 1) * 2;
    const int wq0 = c * 128 + w * 32;
    const int qrow = wq0 + l31;

    short8 qf[4];
    {
      const unsigned short* qp = Q + (size_t)qrow * DIM_ + h * HDIM + hi * 8;
#pragma unroll
      for (int dblk = 0; dblk < 4; ++dblk) qf[dblk] = *(const short8*)(qp + dblk * 16);
    }
    f32x16 o[2] = {};
    float mrun = -1e30f, lrun = 0.f;

    // prologue: stage tile 0 -> buf 0
#pragma unroll
    for (int r = 0; r < 2; ++r) {
      gload_lds16((const char*)Kc + (((size_t)srow[r] * KVDIM + kvcol) << 1) + scolb[r],
                  smem + r * 4096 + w * 1024);
      gload_lds16((const char*)Vt + (((size_t)(kvcol + srow[r]) * SLEN) << 1) + scolb[r],
                  smem + 16384 + r * 4096 + w * 1024);
    }
    __syncthreads();

    for (int t = 0; t < nt; ++t) {
      const int cur = t & 1;
      const int k0 = t * 64;
      if (t + 1 < nt) {
        const int nb = cur ^ 1;
        const int k0n = k0 + 64;
#pragma unroll
        for (int r = 0; r < 2; ++r) {
          gload_lds16((const char*)Kc + (((size_t)(k0n + srow[r]) * KVDIM + kvcol) << 1) + scolb[r],
                      smem + nb * 8192 + r * 4096 + w * 1024);
          gload_lds16((const char*)Vt + (((size_t)(kvcol + srow[r]) * SLEN + k0n) << 1) + scolb[r],
                      smem + 16384 + nb * 8192 + r * 4096 + w * 1024);
        }
      }
      if (k0 <= wq0 + 31) {  // tile visible to this warp
        const char* sK = smem + cur * 8192;
        const char* sV = smem + 16384 + cur * 8192;
        // S^T = K . Q^T : lane owns q = wq0+l31, k = k0 + (r&3)+8*(r>>2)+4*hi (+32 in s1)
        f32x16 s0 = {}, s1 = {};
        __builtin_amdgcn_s_setprio(1);
#pragma unroll
        for (int dblk = 0; dblk < 4; ++dblk) {
          const int colb = (dblk * 32 + hi * 16) ^ ((l31 & 7) << 4);
          short8 kf0 = *(const short8*)(sK + l31 * 128 + colb);
          short8 kf1 = *(const short8*)(sK + (32 + l31) * 128 + colb);
          s0 = __builtin_amdgcn_mfma_f32_32x32x16_bf16(kf0, qf[dblk], s0, 0, 0, 0);
          s1 = __builtin_amdgcn_mfma_f32_32x32x16_bf16(kf1, qf[dblk], s1, 0, 0, 0);
        }
        __builtin_amdgcn_s_setprio(0);

        float p[32];
#pragma unroll
        for (int r = 0; r < 16; ++r) { p[r] = s0[r]; p[16 + r] = s1[r]; }
        if (k0 + 63 > wq0) {  // boundary tile: causal mask
#pragma unroll
          for (int r = 0; r < 16; ++r) {
            const int ka = k0 + (r & 3) + 8 * (r >> 2) + 4 * hi;
            if (ka > qrow) p[r] = -1e30f;
            if (ka + 32 > qrow) p[16 + r] = -1e30f;
          }
        }
        float mt = p[0];
#pragma unroll
        for (int i = 1; i < 32; ++i) mt = fmaxf(mt, p[i]);
        mt = fmaxf(mt, __shfl_xor(mt, 32));
        const float mnew = fmaxf(mrun, mt);
        const float alpha = exp2f(mrun - mnew);
        mrun = mnew;
        float rs = 0.f;
#pragma unroll
        for (int i = 0; i < 32; ++i) { p[i] = exp2f(p[i] - mnew); rs += p[i]; }
        rs += __shfl_xor(rs, 32);
        lrun = lrun * alpha + rs;
#pragma unroll
        for (int r = 0; r < 16; ++r) { o[0][r] *= alpha; o[1][r] *= alpha; }

        // pack P -> bf16 pairs; exchange halves (lane ^ 32) to build PV A-frags
        unsigned pa[8], pb[8], sa[8], sb[8];
#pragma unroll
        for (int i = 0; i < 8; ++i) {
          pa[i] = pack2bf(p[i * 4 + 0], p[i * 4 + 1]);
          pb[i] = pack2bf(p[i * 4 + 2], p[i * 4 + 3]);
        }
#pragma unroll
        for (int i = 0; i < 8; ++i) {
          sa[i] = __shfl_xor((int)pa[i], 32);
          sb[i] = __shfl_xor((int)pb[i], 32);
        }
        // O^T += V^T . P^T  (keeps q = l31 lane-local for m/l/alpha)
        __builtin_amdgcn_s_setprio(1);
#pragma unroll
        for (int kb = 0; kb < 4; ++kb) {
          const int i0 = (kb >> 1) * 4 + (kb & 1) * 2;
          const int i1 = i0 + 1;
          const unsigned w0 = hi ? sa[i1] : pa[i0];
          const unsigned w1 = hi ? sb[i1] : pb[i0];
          const unsigned w2 = hi ? pa[i1] : sa[i0];
          const unsigned w3 = hi ? pb[i1] : sb[i0];
          u32x4 uu = {w0, w1, w2, w3};
          short8 pf = __builtin_bit_cast(short8, uu);
          const int colb = (kb * 32 + hi * 16) ^ ((l31 & 7) << 4);
          short8 vf0 = *(const short8*)(sV + l31 * 128 + colb);
          short8 vf1 = *(const short8*)(sV + (32 + l31) * 128 + colb);
          o[0] = __builtin_amdgcn_mfma_f32_32x32x16_bf16(vf0, pf, o[0], 0, 0, 0);
          o[1] = __builtin_amdgcn_mfma_f32_32x32x16_bf16(vf1, pf, o[1], 0, 0, 0);
        }
        __builtin_amdgcn_s_setprio(0);
      }
      __syncthreads();
    }

    // epilogue: O^T -> LDS (per-warp 4KB, 16B-XOR swizzle) -> coalesced AO rows
    const float inv = 1.0f / lrun;
    char* tw = smem + w * 4096;
#pragma unroll
    for (int db = 0; db < 2; ++db)
#pragma unroll
      for (int g = 0; g < 4; ++g) {
        ushort4 v;
        v.x = f2bf(o[db][g * 4 + 0] * inv);
        v.y = f2bf(o[db][g * 4 + 1] * inv);
        v.z = f2bf(o[db][g * 4 + 2] * inv);
        v.w = f2bf(o[db][g * 4 + 3] * inv);
        const int d0 = db * 32 + g * 8 + hi * 4;
        *(ushort4*)(tw + l31 * 128 + ((d0 * 2) ^ ((l31 & 7) << 4))) = v;
      }
    {
      const int rr = l >> 1, cc = (l & 1) * 32;
      unsigned short* ap = AO + (size_t)(c * 128 + w * 32 + rr) * DIM_ + h * HDIM + cc;
#pragma unroll
      for (int pq = 0; pq < 4; ++pq) {
        const int colb = ((cc + pq * 8) * 2) ^ ((rr & 7) << 4);
        short8 v = *(const short8*)(tw + rr * 128 + colb);
        *(short8*)(ap + pq * 8) = v;
      }
    }
    __syncthreads();  // smem reused by next pass staging
  }
}

extern "C" void kernel_launch(void* const* d_in, const int* in_sizes, int n_in,
                              void* d_out, int out_size, void* d_ws, size_t ws_size,
                              hipStream_t stream) {
  const float* x  = (const float*)d_in[0];
  const float* wq = (const float*)d_in[1];
  const float* wk = (const float*)d_in[2];
  const float* wv = (const float*)d_in[3];
  const float* wo = (const float*)d_in[4];
  float* out = (float*)d_out;
  char* ws = (char*)d_ws;
  const size_t MB = 1u << 20;
  unsigned short* bx   = (unsigned short*)(ws + 0 * MB);    // 8 MB
  unsigned short* bqkv = (unsigned short*)(ws + 8 * MB);    // 12 MB (3072x2048)
  unsigned short* bwo  = (unsigned short*)(ws + 20 * MB);   // 8 MB
  unsigned short* Qr   = (unsigned short*)(ws + 28 * MB);   // 8 MB
  unsigned short* Kr   = (unsigned short*)(ws + 36 * MB);   // 2 MB
  unsigned short* Vt   = (unsigned short*)(ws + 38 * MB);   // 2 MB
  unsigned short* AO   = (unsigned short*)(ws + 40 * MB);   // 8 MB
  float* cosT = (float*)(ws + 48 * MB);                     // 256 KB
  float* sinT = (float*)(ws + 48 * MB + 256 * 1024);        // 256 KB

  rope_table_kernel<<<SLEN * 32 / 256, 256, 0, stream>>>(cosT, sinT);
  cvt_bf16_kernel<<<(2048 * 2048 / 8) / 256, 256, 0, stream>>>(x, bx, 2048 * 2048);
  cvt_bf16_kernel<<<(2048 * 2048 / 8) / 256, 256, 0, stream>>>(wq, bqkv, 2048 * 2048);
  cvt_bf16_kernel<<<(512 * 2048 / 8) / 256, 256, 0, stream>>>(wk, bqkv + 2048 * 2048, 512 * 2048);
  cvt_bf16_kernel<<<(512 * 2048 / 8) / 256, 256, 0, stream>>>(wv, bqkv + 2560 * 2048, 512 * 2048);
  cvt_bf16_kernel<<<(2048 * 2048 / 8) / 256, 256, 0, stream>>>(wo, bwo, 2048 * 2048);

  gemm_qkv<<<dim3(16, 24), 256, 0, stream>>>(bx, bqkv, Qr, Kr, Vt, cosT, sinT);

  attn2_kernel<<<dim3(8, 32), 256, 0, stream>>>(Qr, Kr, Vt, AO);

  gemm_bt_f32<<<dim3(16, 16), 256, 0, stream>>>(AO, bwo, out);
}